// Round 4
// baseline (194.846 us; speedup 1.0000x reference)
//
#include <hip/hip_runtime.h>

// ComboSumModule: six independent sum-over-axis-1 reductions (f32).
// Shapes: (2048,128,64) (2048,32,32) (2048,64,64) (2048,16,48)
//         (2048,200,32) (2048,8,8). Outputs concatenated flat.
//
// R9: the harness's own 268MB poison fill runs at 6.63 TB/s (83% peak) on
// this chip -- the memory system services LINEAR streams at full rate,
// while our strided-segment reads (4x256B / 8x128B scattered wave-loads)
// pinned at 2.4-2.8 TB/s across four structures. R7 had the contiguous
// slab structure (every wave-load = one 1KB linear segment) but no nt and
// a pipeline the compiler collapsed (WAR trick -> VGPR 32). R8 had nt but
// the strided structure. R9 = both: contiguous slabs + ntload + R6-style
// sched_barrier(0) fences (proven to hold buffers live), double-buffer
// B=4 (~56 VGPR) so launch_bounds(256,8) holds 32 waves/CU and all 1776
// blocks are co-resident in one generation. No LDS, no barriers.
// Predicted: VGPR 56-64, occ 70-90%, dispatch 25-35us, hbm_gbps 4-6 TB/s,
// FETCH ~150MB. Pre-commit: if this ties R8 (~56us/dispatch, healthy
// occupancy, no spills), the ~2.7 TB/s read ceiling is real across every
// lever combination -> declare ROOFLINE next round.

typedef float f32x4 __attribute__((ext_vector_type(4)));

__device__ __forceinline__ float4 ntload(const float4* __restrict__ p) {
  f32x4 v = __builtin_nontemporal_load(reinterpret_cast<const f32x4*>(p));
  return make_float4(v.x, v.y, v.z, v.w);
}

__device__ __forceinline__ float4 f4add(float4 a, float4 b) {
  return make_float4(a.x + b.x, a.y + b.y, a.z + b.z, a.w + b.w);
}

__device__ __forceinline__ float4 f4zero() {
  return make_float4(0.f, 0.f, 0.f, 0.f);
}

__device__ __forceinline__ float4 shfl_xor_add(float4 r, int off) {
  r.x += __shfl_xor(r.x, off);
  r.y += __shfl_xor(r.y, off);
  r.z += __shfl_xor(r.z, off);
  r.w += __shfl_xor(r.w, off);
  return r;
}

template <int STRIDE4, int B>
__device__ __forceinline__ void load_batch(float4 (&v)[B],
                                           const float4* __restrict__ q) {
#pragma unroll
  for (int i = 0; i < B; ++i) v[i] = ntload(q + (size_t)i * STRIDE4);
}

template <int B>
__device__ __forceinline__ void add_batch(const float4 (&v)[B], float4& a0,
                                          float4& a1) {
#pragma unroll
  for (int i = 0; i < B; ++i) {
    if (i & 1) a1 = f4add(a1, v[i]);
    else a0 = f4add(a0, v[i]);
  }
}

// Double-buffered streaming sum: ROWS loads at stride STRIDE4, batches of
// B=4, two buffers. sched_barrier(0) between load-block and add-block pins
// program order (R6 verified this holds all buffers live, VGPR=64): loads
// of batch k+1 issue before adds of batch k -> vmcnt(B) partial waits,
// 4-8 loads perpetually in flight per wave.
template <int ROWS, int STRIDE4>
__device__ __forceinline__ float4 dbuf_sum(const float4* __restrict__ p) {
  constexpr int B = (ROWS >= 4) ? 4 : ROWS;
  constexpr int NB = ROWS / B;
  constexpr int TAIL = ROWS - NB * B;

  float4 va[B], vb[B];
  float4 a0 = f4zero(), a1 = f4zero();

  load_batch<STRIDE4>(va, p);
  __builtin_amdgcn_sched_barrier(0);

#pragma unroll
  for (int k = 1; k < NB; ++k) {
    const float4* q = p + (size_t)(k * B) * STRIDE4;
    if (k & 1) {
      load_batch<STRIDE4>(vb, q);
      __builtin_amdgcn_sched_barrier(0);
      add_batch(va, a0, a1);
    } else {
      load_batch<STRIDE4>(va, q);
      __builtin_amdgcn_sched_barrier(0);
      add_batch(vb, a0, a1);
    }
    __builtin_amdgcn_sched_barrier(0);
  }

  if constexpr (TAIL > 0) {
    float4 vt[TAIL];
    load_batch<STRIDE4>(vt, p + (size_t)(NB * B) * STRIDE4);
    __builtin_amdgcn_sched_barrier(0);
    if constexpr (((NB - 1) & 1) != 0) add_batch(vb, a0, a1);
    else add_batch(va, a0, a1);
    add_batch(vt, a0, a1);
  } else {
    if constexpr (((NB - 1) & 1) != 0) add_batch(vb, a0, a1);
    else add_batch(va, a0, a1);
  }
  return f4add(a0, a1);
}

// One wave sums one whole batch slab (M*N4 float4s, CONTIGUOUS: lane
// reads f4 index i*64+lane -- each wave-load is one linear 1KB segment,
// the same address stream the 6.6TB/s fill kernel produces). 64%N4==0 so
// a lane's column is invariant (lane & (N4-1)); shfl_xor over {N4..32}
// combines the 64/N4 row-groups; lanes<N4 store.
template <int M, int N4>
__device__ __forceinline__ void slab_sum(const float* __restrict__ xp,
                                         float4* __restrict__ outp, int b,
                                         int lane) {
  constexpr int L = M * N4 / 64;
  const float4* p =
      reinterpret_cast<const float4*>(xp) + (size_t)b * (M * N4) + lane;
  float4 r = dbuf_sum<L, 64>(p);
#pragma unroll
  for (int off = N4; off < 64; off <<= 1) r = shfl_xor_add(r, off);
  if (lane < N4) outp[(size_t)b * N4 + lane] = r;
}

// x1 (M=32,N4=8): slab is 4KB; one wave streams 4 consecutive batches
// (16 contiguous 1KB loads). Group j (4 loads) == batch j exactly;
// alternate buffers, reduce+store per group to keep the live set small.
__device__ __forceinline__ void x1_quad(const float* __restrict__ xp,
                                        float4* __restrict__ outp, int w,
                                        int lane) {
  const int b0 = w << 2;
  const float4* p =
      reinterpret_cast<const float4*>(xp) + (size_t)b0 * 256 + lane;
  float4 va[4], vb[4];
  load_batch<64>(va, p);
  __builtin_amdgcn_sched_barrier(0);
#pragma unroll
  for (int j = 0; j < 4; ++j) {
    if (j < 3) {
      if (j & 1) load_batch<64>(va, p + (size_t)(j + 1) * 256);
      else load_batch<64>(vb, p + (size_t)(j + 1) * 256);
      __builtin_amdgcn_sched_barrier(0);
    }
    float4 r;
    if (j & 1) r = f4add(f4add(vb[0], vb[1]), f4add(vb[2], vb[3]));
    else r = f4add(f4add(va[0], va[1]), f4add(va[2], va[3]));
    r = shfl_xor_add(r, 8);
    r = shfl_xor_add(r, 16);
    r = shfl_xor_add(r, 32);
    if (lane < 8) outp[(size_t)(b0 + j) * 8 + lane] = r;
    __builtin_amdgcn_sched_barrier(0);
  }
}

// Column-walk for tensors where 64%N4 != 0 (x3, N4=12) or slabs are tiny
// (x5): lane owns output unit u, walks M rows at stride N4. 3.7% of bytes.
template <int M, int N4>
__device__ __forceinline__ void col_walk(const float* __restrict__ xp,
                                         float4* __restrict__ outp, int task,
                                         int lane) {
  const int u = task * 64 + lane;
  const int b = u / N4;  // const divisor -> magic-mul
  const int n4 = u - b * N4;
  const float4* p =
      reinterpret_cast<const float4*>(xp) + (size_t)b * (M * N4) + n4;
  outp[u] = dbuf_sum<M, N4>(p);
}

// Wave map (4 waves/block, all region boundaries block-uniform):
//   blk [   0, 512): x0 M=128 N4=16, 1 batch/wave  (32 loads, 32KB)
//   blk [ 512,1024): x4 M=200 N4= 8, 1 batch/wave  (25 loads, 25KB)
//   blk [1024,1536): x2 M= 64 N4=16, 1 batch/wave  (16 loads, 16KB)
//   blk [1536,1664): x1 M= 32 N4= 8, 4 batches/wave(16 loads, 16KB)
//   blk [1664,1760): x3 col-walk    (16 loads/lane, 16KB/wave)
//   blk [1760,1776): x5 col-walk    ( 8 loads/lane,  8KB/wave)
// Output float4 bases: x0 0, x1 32768, x2 49152, x3 81920, x4 106496,
// x5 122880 (outputs concatenated in input order).
__global__ __launch_bounds__(256, 8) void ComboSumModule_25314537242674_kernel(
    const float* __restrict__ x0, const float* __restrict__ x1,
    const float* __restrict__ x2, const float* __restrict__ x3,
    const float* __restrict__ x4, const float* __restrict__ x5,
    float* __restrict__ out) {
  const int lane = threadIdx.x & 63;
  const int wave = threadIdx.x >> 6;
  const int blk = blockIdx.x;
  float4* out4 = reinterpret_cast<float4*>(out);

  if (blk < 512) {
    slab_sum<128, 16>(x0, out4 + 0, (blk << 2) | wave, lane);
  } else if (blk < 1024) {
    slab_sum<200, 8>(x4, out4 + 106496, ((blk - 512) << 2) | wave, lane);
  } else if (blk < 1536) {
    slab_sum<64, 16>(x2, out4 + 49152, ((blk - 1024) << 2) | wave, lane);
  } else if (blk < 1664) {
    x1_quad(x1, out4 + 32768, ((blk - 1536) << 2) | wave, lane);
  } else if (blk < 1760) {
    col_walk<16, 12>(x3, out4 + 81920, ((blk - 1664) << 2) | wave, lane);
  } else {
    col_walk<8, 2>(x5, out4 + 122880, ((blk - 1760) << 2) | wave, lane);
  }
}

extern "C" void kernel_launch(void* const* d_in, const int* in_sizes, int n_in,
                              void* d_out, int out_size, void* d_ws,
                              size_t ws_size, hipStream_t stream) {
  const float* x0 = (const float*)d_in[0];
  const float* x1 = (const float*)d_in[1];
  const float* x2 = (const float*)d_in[2];
  const float* x3 = (const float*)d_in[3];
  const float* x4 = (const float*)d_in[4];
  const float* x5 = (const float*)d_in[5];
  // d_in[6] is the python scalar dim=1; reduction axis baked in.
  float* out = (float*)d_out;

  ComboSumModule_25314537242674_kernel<<<1776, 256, 0, stream>>>(x0, x1, x2,
                                                                 x3, x4, x5,
                                                                 out);
}

// Round 5
// 169.167 us; speedup vs baseline: 1.1518x; 1.1518x over previous
//
#include <hip/hip_runtime.h>

// ComboSumModule: six independent sum-over-axis-1 reductions (f32).
// Shapes: (2048,128,64) (2048,32,32) (2048,64,64) (2048,16,48)
//         (2048,200,32) (2048,8,8). Outputs concatenated flat.
//
// R10: R9's contiguous+nt+dbuf structure was invalidated by a spill bug:
// launch_bounds(256,8) (64-VGPR cap) under the sched_barrier-pinned
// schedule made RA dump the buffers to scratch -- WRITE_SIZE 70MB vs 2MB
// output, 140MB scratch round-trip/dispatch, VGPR=32. Fix: ONLY change
// launch_bounds to (256,4) (128-VGPR cap, ~50 live -> no spill possible;
// R6 proved this fence pattern holds buffers live at these bounds).
// Forensic notes driving this: (a) the 256-MiB fills between iterations
// are L3 FLUSHES -- cached reads then force ~160MB invisible L3 dirty
// writeback during our kernel; nt loads skip L3 allocation and avoid it;
// (b) R8 (nt, no spills) was session-best and its kernel ran BELOW the
// 40.5us fills in its rocprof capture -- only sub-41us evidence all
// session; (c) R9 moved 192MB at 3.2TB/s in the same 60us -- the pipe
// has headroom when asked.
// Predicted: WRITE_SIZE 71840 -> ~2-10MB (key check: scratch gone),
// VGPR 48-64, occ >=70%, dispatch 35-45us, harness <=~140us. Pre-commit:
// clean counters + dispatch still 55-62us => declare ROOFLINE.

typedef float f32x4 __attribute__((ext_vector_type(4)));

__device__ __forceinline__ float4 ntload(const float4* __restrict__ p) {
  f32x4 v = __builtin_nontemporal_load(reinterpret_cast<const f32x4*>(p));
  return make_float4(v.x, v.y, v.z, v.w);
}

__device__ __forceinline__ float4 f4add(float4 a, float4 b) {
  return make_float4(a.x + b.x, a.y + b.y, a.z + b.z, a.w + b.w);
}

__device__ __forceinline__ float4 f4zero() {
  return make_float4(0.f, 0.f, 0.f, 0.f);
}

__device__ __forceinline__ float4 shfl_xor_add(float4 r, int off) {
  r.x += __shfl_xor(r.x, off);
  r.y += __shfl_xor(r.y, off);
  r.z += __shfl_xor(r.z, off);
  r.w += __shfl_xor(r.w, off);
  return r;
}

template <int STRIDE4, int B>
__device__ __forceinline__ void load_batch(float4 (&v)[B],
                                           const float4* __restrict__ q) {
#pragma unroll
  for (int i = 0; i < B; ++i) v[i] = ntload(q + (size_t)i * STRIDE4);
}

template <int B>
__device__ __forceinline__ void add_batch(const float4 (&v)[B], float4& a0,
                                          float4& a1) {
#pragma unroll
  for (int i = 0; i < B; ++i) {
    if (i & 1) a1 = f4add(a1, v[i]);
    else a0 = f4add(a0, v[i]);
  }
}

// Double-buffered streaming sum: ROWS loads at stride STRIDE4, batches of
// B=4, two buffers. sched_barrier(0) between load-block and add-block pins
// program order: loads of batch k+1 issue before adds of batch k ->
// vmcnt(B) partial waits, 4-8 loads perpetually in flight per wave.
// ~50 live VGPRs; with the 128-VGPR cap of launch_bounds(256,4) the RA
// cannot be forced to spill (R9's failure mode).
template <int ROWS, int STRIDE4>
__device__ __forceinline__ float4 dbuf_sum(const float4* __restrict__ p) {
  constexpr int B = (ROWS >= 4) ? 4 : ROWS;
  constexpr int NB = ROWS / B;
  constexpr int TAIL = ROWS - NB * B;

  float4 va[B], vb[B];
  float4 a0 = f4zero(), a1 = f4zero();

  load_batch<STRIDE4>(va, p);
  __builtin_amdgcn_sched_barrier(0);

#pragma unroll
  for (int k = 1; k < NB; ++k) {
    const float4* q = p + (size_t)(k * B) * STRIDE4;
    if (k & 1) {
      load_batch<STRIDE4>(vb, q);
      __builtin_amdgcn_sched_barrier(0);
      add_batch(va, a0, a1);
    } else {
      load_batch<STRIDE4>(va, q);
      __builtin_amdgcn_sched_barrier(0);
      add_batch(vb, a0, a1);
    }
    __builtin_amdgcn_sched_barrier(0);
  }

  if constexpr (TAIL > 0) {
    float4 vt[TAIL];
    load_batch<STRIDE4>(vt, p + (size_t)(NB * B) * STRIDE4);
    __builtin_amdgcn_sched_barrier(0);
    if constexpr (((NB - 1) & 1) != 0) add_batch(vb, a0, a1);
    else add_batch(va, a0, a1);
    add_batch(vt, a0, a1);
  } else {
    if constexpr (((NB - 1) & 1) != 0) add_batch(vb, a0, a1);
    else add_batch(va, a0, a1);
  }
  return f4add(a0, a1);
}

// One wave sums one whole batch slab (M*N4 float4s, CONTIGUOUS: lane
// reads f4 index i*64+lane -- each wave-load is one linear 1KB segment).
// 64%N4==0 so a lane's column is invariant (lane & (N4-1)); shfl_xor over
// {N4..32} combines the 64/N4 row-groups; lanes<N4 store.
template <int M, int N4>
__device__ __forceinline__ void slab_sum(const float* __restrict__ xp,
                                         float4* __restrict__ outp, int b,
                                         int lane) {
  constexpr int L = M * N4 / 64;
  const float4* p =
      reinterpret_cast<const float4*>(xp) + (size_t)b * (M * N4) + lane;
  float4 r = dbuf_sum<L, 64>(p);
#pragma unroll
  for (int off = N4; off < 64; off <<= 1) r = shfl_xor_add(r, off);
  if (lane < N4) outp[(size_t)b * N4 + lane] = r;
}

// x1 (M=32,N4=8): slab is 4KB; one wave streams 4 consecutive batches
// (16 contiguous 1KB loads). Group j (4 loads) == batch j exactly;
// alternate buffers, reduce+store per group to keep the live set small.
__device__ __forceinline__ void x1_quad(const float* __restrict__ xp,
                                        float4* __restrict__ outp, int w,
                                        int lane) {
  const int b0 = w << 2;
  const float4* p =
      reinterpret_cast<const float4*>(xp) + (size_t)b0 * 256 + lane;
  float4 va[4], vb[4];
  load_batch<64>(va, p);
  __builtin_amdgcn_sched_barrier(0);
#pragma unroll
  for (int j = 0; j < 4; ++j) {
    if (j < 3) {
      if (j & 1) load_batch<64>(va, p + (size_t)(j + 1) * 256);
      else load_batch<64>(vb, p + (size_t)(j + 1) * 256);
      __builtin_amdgcn_sched_barrier(0);
    }
    float4 r;
    if (j & 1) r = f4add(f4add(vb[0], vb[1]), f4add(vb[2], vb[3]));
    else r = f4add(f4add(va[0], va[1]), f4add(va[2], va[3]));
    r = shfl_xor_add(r, 8);
    r = shfl_xor_add(r, 16);
    r = shfl_xor_add(r, 32);
    if (lane < 8) outp[(size_t)(b0 + j) * 8 + lane] = r;
    __builtin_amdgcn_sched_barrier(0);
  }
}

// Column-walk for tensors where 64%N4 != 0 (x3, N4=12) or slabs are tiny
// (x5): lane owns output unit u, walks M rows at stride N4. 3.7% of bytes.
template <int M, int N4>
__device__ __forceinline__ void col_walk(const float* __restrict__ xp,
                                         float4* __restrict__ outp, int task,
                                         int lane) {
  const int u = task * 64 + lane;
  const int b = u / N4;  // const divisor -> magic-mul
  const int n4 = u - b * N4;
  const float4* p =
      reinterpret_cast<const float4*>(xp) + (size_t)b * (M * N4) + n4;
  outp[u] = dbuf_sum<M, N4>(p);
}

// Wave map (4 waves/block, all region boundaries block-uniform):
//   blk [   0, 512): x0 M=128 N4=16, 1 batch/wave  (32 loads, 32KB)
//   blk [ 512,1024): x4 M=200 N4= 8, 1 batch/wave  (25 loads, 25KB)
//   blk [1024,1536): x2 M= 64 N4=16, 1 batch/wave  (16 loads, 16KB)
//   blk [1536,1664): x1 M= 32 N4= 8, 4 batches/wave(16 loads, 16KB)
//   blk [1664,1760): x3 col-walk    (16 loads/lane, 16KB/wave)
//   blk [1760,1776): x5 col-walk    ( 8 loads/lane,  8KB/wave)
// Output float4 bases: x0 0, x1 32768, x2 49152, x3 81920, x4 106496,
// x5 122880 (outputs concatenated in input order).
__global__ __launch_bounds__(256, 4) void ComboSumModule_25314537242674_kernel(
    const float* __restrict__ x0, const float* __restrict__ x1,
    const float* __restrict__ x2, const float* __restrict__ x3,
    const float* __restrict__ x4, const float* __restrict__ x5,
    float* __restrict__ out) {
  const int lane = threadIdx.x & 63;
  const int wave = threadIdx.x >> 6;
  const int blk = blockIdx.x;
  float4* out4 = reinterpret_cast<float4*>(out);

  if (blk < 512) {
    slab_sum<128, 16>(x0, out4 + 0, (blk << 2) | wave, lane);
  } else if (blk < 1024) {
    slab_sum<200, 8>(x4, out4 + 106496, ((blk - 512) << 2) | wave, lane);
  } else if (blk < 1536) {
    slab_sum<64, 16>(x2, out4 + 49152, ((blk - 1024) << 2) | wave, lane);
  } else if (blk < 1664) {
    x1_quad(x1, out4 + 32768, ((blk - 1536) << 2) | wave, lane);
  } else if (blk < 1760) {
    col_walk<16, 12>(x3, out4 + 81920, ((blk - 1664) << 2) | wave, lane);
  } else {
    col_walk<8, 2>(x5, out4 + 122880, ((blk - 1760) << 2) | wave, lane);
  }
}

extern "C" void kernel_launch(void* const* d_in, const int* in_sizes, int n_in,
                              void* d_out, int out_size, void* d_ws,
                              size_t ws_size, hipStream_t stream) {
  const float* x0 = (const float*)d_in[0];
  const float* x1 = (const float*)d_in[1];
  const float* x2 = (const float*)d_in[2];
  const float* x3 = (const float*)d_in[3];
  const float* x4 = (const float*)d_in[4];
  const float* x5 = (const float*)d_in[5];
  // d_in[6] is the python scalar dim=1; reduction axis baked in.
  float* out = (float*)d_out;

  ComboSumModule_25314537242674_kernel<<<1776, 256, 0, stream>>>(x0, x1, x2,
                                                                 x3, x4, x5,
                                                                 out);
}